// Round 14
// baseline (1879.239 us; speedup 1.0000x reference)
//
#include <hip/hip_runtime.h>

// ---------------------------------------------------------------------------
// NodeNetwork: agg(sum over deg=16) -> concat(3x128) -> MLP(384-256-256-128)
//              -> row L2 normalize.  N=500000 rows.
// R14: PRODUCER/CONSUMER WAVE SPECIALIZATION (persistent, double-buffered).
// 512 threads: waves 0-3 = MLP (R9's exact structure), waves 4-7 = streamers
// filling the OTHER X-buffer with the next tile while the MLP runs. A
// barrier's vmcnt drain is per-wave, so streamer drains never stall MFMA;
// streaming continues through the whole MLP -> HBM duty ~95% (vs R9's ~70%).
// LDS 80KB: XB0 24K | XB1 24K | h1 16K | h2 16K (out reuses h1) -> 2 blk/CU.
// ---------------------------------------------------------------------------

typedef short short8   __attribute__((ext_vector_type(8)));
typedef short short4_t __attribute__((ext_vector_type(4)));
typedef float f32x4    __attribute__((ext_vector_type(4)));

#define SWZ(row, off) ((off) ^ (((row) & 7) << 4))

__device__ __forceinline__ unsigned short f2bf(float f) {
    unsigned int u = __float_as_uint(f);
    u += 0x7fffu + ((u >> 16) & 1u);   // round-to-nearest-even
    return (unsigned short)(u >> 16);
}

// ---------------------------------------------------------------------------
// Weight prep (unchanged): fp32->bf16, per-lane MFMA B-fragment order:
//   pw[((tn*KS + ks)*64 + lane)*8 + j] = bf16( W[k][n] )
//   n = tn*16 + (lane&15), k = ks*32 + (lane>>4)*8 + j
// ---------------------------------------------------------------------------
__global__ void prep_weights(const float* __restrict__ W1,
                             const float* __restrict__ W2,
                             const float* __restrict__ W3,
                             short* __restrict__ pw1,
                             short* __restrict__ pw2,
                             short* __restrict__ pw3) {
    int idx = blockIdx.x * 256 + threadIdx.x;
    if (idx < 98304) {                       // W1 [384][256]
        int j = idx & 7, l = (idx >> 3) & 63, g = idx >> 9;
        int ks = g % 12, tn = g / 12;
        int n = tn * 16 + (l & 15);
        int k = ks * 32 + ((l >> 4) << 3) + j;
        pw1[idx] = (short)f2bf(W1[k * 256 + n]);
    } else if (idx < 98304 + 65536) {        // W2 [256][256]
        int e = idx - 98304;
        int j = e & 7, l = (e >> 3) & 63, g = e >> 9;
        int ks = g & 7, tn = g >> 3;
        int n = tn * 16 + (l & 15);
        int k = ks * 32 + ((l >> 4) << 3) + j;
        pw2[e] = (short)f2bf(W2[k * 256 + n]);
    } else if (idx < 98304 + 65536 + 32768) { // W3 [256][128]
        int e = idx - 98304 - 65536;
        int j = e & 7, l = (e >> 3) & 63, g = e >> 9;
        int ks = g & 7, tn = g >> 3;
        int n = tn * 16 + (l & 15);
        int k = ks * 32 + ((l >> 4) << 3) + j;
        pw3[e] = (short)f2bf(W3[k * 128 + n]);
    }
}

// ---- streamer helpers -----------------------------------------------------
// One msg row-pair: 16 x 1KB wave-contiguous NT loads, shfl merge, bf16->LDS.
__device__ __forceinline__ void stream_pair(
    const float* __restrict__ msg, char* aggdst,
    long long rn0, int sw, int pp, int lane, int n_rows)
{
    const f32x4 zero4 = {0.f, 0.f, 0.f, 0.f};
    const int rA = 8 * sw + 2 * pp;
    const long long rowA = rn0 + rA;
    const f32x4* base = (const f32x4*)msg + rowA * 512;
    const bool okA = rowA < n_rows;
    const bool okB = (rowA + 1) < n_rows;
    f32x4 tA[8], tB[8];
    #pragma unroll
    for (int i = 0; i < 8; ++i)
        tA[i] = okA ? __builtin_nontemporal_load(base + i * 64 + lane) : zero4;
    #pragma unroll
    for (int i = 0; i < 8; ++i)
        tB[i] = okB ? __builtin_nontemporal_load(base + 512 + i * 64 + lane) : zero4;
    f32x4 sA = ((tA[0]+tA[1])+(tA[2]+tA[3])) + ((tA[4]+tA[5])+(tA[6]+tA[7]));
    f32x4 sB = ((tB[0]+tB[1])+(tB[2]+tB[3])) + ((tB[4]+tB[5])+(tB[6]+tB[7]));
    #pragma unroll
    for (int c = 0; c < 4; ++c) {
        sA[c] += __shfl_xor(sA[c], 32);
        sB[c] += __shfl_xor(sB[c], 32);
    }
    f32x4 s = (lane < 32) ? sA : sB;
    short4_t s4;
    s4[0] = (short)f2bf(s[0]); s4[1] = (short)f2bf(s[1]);
    s4[2] = (short)f2bf(s[2]); s4[3] = (short)f2bf(s[3]);
    const int orow = rA + (lane >> 5);
    *(short4_t*)(aggdst + SWZ(orow, orow * 256 + (lane & 31) * 8)) = s4;
}

// feat/glob for this streamer wave's 8 rows -> XB regions (NT loads).
__device__ __forceinline__ void stream_fg(
    const float* __restrict__ feat, const float* __restrict__ glob,
    char* xbdst, long long rn0, int sw, int lane, int n_rows)
{
    const f32x4 zero4 = {0.f, 0.f, 0.f, 0.f};
    const int rl = 8 * sw + (lane >> 3);
    const long long grow = rn0 + rl;
    const bool ok = grow < n_rows;
    #pragma unroll
    for (int q = 0; q < 4; ++q) {
        const int f = (lane & 7) * 4 + q;
        f32x4 fv = ok ? __builtin_nontemporal_load((const f32x4*)feat + grow * 32 + f) : zero4;
        f32x4 gv = ok ? __builtin_nontemporal_load((const f32x4*)glob + grow * 32 + f) : zero4;
        short4_t sf, sg;
        sf[0]=(short)f2bf(fv[0]); sf[1]=(short)f2bf(fv[1]);
        sf[2]=(short)f2bf(fv[2]); sf[3]=(short)f2bf(fv[3]);
        sg[0]=(short)f2bf(gv[0]); sg[1]=(short)f2bf(gv[1]);
        sg[2]=(short)f2bf(gv[2]); sg[3]=(short)f2bf(gv[3]);
        *(short4_t*)(xbdst + 8192  + SWZ(rl, rl * 256 + f * 8)) = sf;
        *(short4_t*)(xbdst + 16384 + SWZ(rl, rl * 256 + f * 8)) = sg;
    }
}

// ---------------------------------------------------------------------------
// Persistent producer/consumer kernel. 512 threads, 80KB LDS, 2 blocks/CU.
// ---------------------------------------------------------------------------
__global__ __launch_bounds__(512, 2) void node_net_pc(
    const float* __restrict__ msg,
    const float* __restrict__ feat,
    const float* __restrict__ glob,
    const float* __restrict__ b1v,
    const float* __restrict__ b2v,
    const float* __restrict__ b3v,
    const short* __restrict__ pw1,
    const short* __restrict__ pw2,
    const short* __restrict__ pw3,
    float* __restrict__ out,
    int n_rows, int ntiles, int nblk)
{
    __shared__ char lds[81920];
    char* H1 = lds + 49152;        // h1 bf16 [32][256] (16KB); later out f32
    char* H2 = lds + 65536;        // h2 bf16 [32][256] (16KB)

    const int tid  = threadIdx.x;
    const int lane = tid & 63;
    const int w    = tid >> 6;            // 0..7
    const bool is_mlp = (w < 4);
    const int sw   = w - 4;               // streamer wave id 0..3
    const int lr   = lane & 15;
    const int lk   = lane >> 4;
    const f32x4 zero4 = {0.f, 0.f, 0.f, 0.f};

    // ---- bias prefetch (MLP waves only; w<4 so indices in range) ----
    float bias1[4] = {0,0,0,0}, bias2[4] = {0,0,0,0}, bias3[2] = {0,0};
    if (is_mlp) {
        #pragma unroll
        for (int ci = 0; ci < 4; ++ci) {
            bias1[ci] = b1v[w * 64 + ci * 16 + lr];
            bias2[ci] = b2v[w * 64 + ci * 16 + lr];
        }
        #pragma unroll
        for (int ci = 0; ci < 2; ++ci) bias3[ci] = b3v[w * 32 + ci * 16 + lr];
    }

    long long t = blockIdx.x;
    int p = 0;

    // ---- prologue: streamers fill XB0 with x(t0) ----
    if (!is_mlp) {
        const long long r0 = t * 32;
        #pragma unroll 1
        for (int pp = 0; pp < 4; ++pp)
            stream_pair(msg, lds + 0, r0, sw, pp, lane, n_rows);
        stream_fg(feat, glob, lds + 0, r0, sw, lane, n_rows);
    }
    __syncthreads();

    // ---- persistent tile loop ----
    for (; t < ntiles; t += nblk, p ^= 1) {
        char* xb = lds + (p ? 24576 : 0);        // current tile's inputs
        char* xn = lds + (p ? 0 : 24576);        // next tile's staging
        const long long r0  = t * 32;
        const long long rn0 = (t + (long long)nblk) * 32;

        f32x4 acc1[2][4];
        // ================= I0: GEMM1 (12 ks) + epi1  ||  2 msg chunks ======
        if (is_mlp) {
            #pragma unroll
            for (int ri = 0; ri < 2; ++ri)
                #pragma unroll
                for (int ci = 0; ci < 4; ++ci) acc1[ri][ci] = zero4;
            #pragma unroll
            for (int ks = 0; ks < 12; ++ks) {
                const int reg = ks >> 2, s = ks & 3;
                short8 a[2], b[4];
                #pragma unroll
                for (int ri = 0; ri < 2; ++ri) {
                    int row = ri * 16 + lr;
                    a[ri] = *(const short8*)(xb + reg * 8192 + SWZ(row, row * 256 + s * 64 + lk * 16));
                }
                #pragma unroll
                for (int ci = 0; ci < 4; ++ci)
                    b[ci] = *(const short8*)(pw1 + ((((w * 4 + ci) * 12 + ks) * 64 + lane) << 3));
                #pragma unroll
                for (int ri = 0; ri < 2; ++ri)
                    #pragma unroll
                    for (int ci = 0; ci < 4; ++ci)
                        acc1[ri][ci] = __builtin_amdgcn_mfma_f32_16x16x32_bf16(
                            a[ri], b[ci], acc1[ri][ci], 0, 0, 0);
            }
            // epi1: +b1, ReLU -> h1 (H1)
            #pragma unroll
            for (int ci = 0; ci < 4; ++ci) {
                int col = w * 64 + ci * 16 + lr;
                #pragma unroll
                for (int ri = 0; ri < 2; ++ri)
                    #pragma unroll
                    for (int i = 0; i < 4; ++i) {
                        int row = ri * 16 + lk * 4 + i;
                        float v = fmaxf(acc1[ri][ci][i] + bias1[ci], 0.f);
                        *(short*)(H1 + SWZ(row, row * 512 + col * 2)) = (short)f2bf(v);
                    }
            }
        } else {
            stream_pair(msg, xn, rn0, sw, 0, lane, n_rows);
            stream_pair(msg, xn, rn0, sw, 1, lane, n_rows);
        }
        __syncthreads();                                   // b1

        // ================= I1: GEMM2 + epi2  ||  1 msg chunk ===============
        if (is_mlp) {
            f32x4 acc2[2][4];
            #pragma unroll
            for (int ri = 0; ri < 2; ++ri)
                #pragma unroll
                for (int ci = 0; ci < 4; ++ci) acc2[ri][ci] = zero4;
            #pragma unroll
            for (int s = 0; s < 8; ++s) {
                short8 a[2], b[4];
                #pragma unroll
                for (int ri = 0; ri < 2; ++ri) {
                    int row = ri * 16 + lr;
                    a[ri] = *(const short8*)(H1 + SWZ(row, row * 512 + s * 64 + lk * 16));
                }
                #pragma unroll
                for (int ci = 0; ci < 4; ++ci)
                    b[ci] = *(const short8*)(pw2 + ((((w * 4 + ci) * 8 + s) * 64 + lane) << 3));
                #pragma unroll
                for (int ri = 0; ri < 2; ++ri)
                    #pragma unroll
                    for (int ci = 0; ci < 4; ++ci)
                        acc2[ri][ci] = __builtin_amdgcn_mfma_f32_16x16x32_bf16(
                            a[ri], b[ci], acc2[ri][ci], 0, 0, 0);
            }
            // epi2 -> h2 (H2)
            #pragma unroll
            for (int ci = 0; ci < 4; ++ci) {
                int col = w * 64 + ci * 16 + lr;
                #pragma unroll
                for (int ri = 0; ri < 2; ++ri)
                    #pragma unroll
                    for (int i = 0; i < 4; ++i) {
                        int row = ri * 16 + lk * 4 + i;
                        float v = fmaxf(acc2[ri][ci][i] + bias2[ci], 0.f);
                        *(short*)(H2 + SWZ(row, row * 512 + col * 2)) = (short)f2bf(v);
                    }
            }
        } else {
            stream_pair(msg, xn, rn0, sw, 2, lane, n_rows);
        }
        __syncthreads();                                   // b2

        // ================= I2: GEMM3 + epi3  ||  1 msg chunk ===============
        if (is_mlp) {
            f32x4 acc3[2][2];
            #pragma unroll
            for (int ri = 0; ri < 2; ++ri)
                #pragma unroll
                for (int ci = 0; ci < 2; ++ci) acc3[ri][ci] = zero4;
            #pragma unroll
            for (int s = 0; s < 8; ++s) {
                short8 a[2], b[2];
                #pragma unroll
                for (int ri = 0; ri < 2; ++ri) {
                    int row = ri * 16 + lr;
                    a[ri] = *(const short8*)(H2 + SWZ(row, row * 512 + s * 64 + lk * 16));
                }
                #pragma unroll
                for (int ci = 0; ci < 2; ++ci)
                    b[ci] = *(const short8*)(pw3 + ((((w * 2 + ci) * 8 + s) * 64 + lane) << 3));
                #pragma unroll
                for (int ri = 0; ri < 2; ++ri)
                    #pragma unroll
                    for (int ci = 0; ci < 2; ++ci)
                        acc3[ri][ci] = __builtin_amdgcn_mfma_f32_16x16x32_bf16(
                            a[ri], b[ci], acc3[ri][ci], 0, 0, 0);
            }
            // epi3: +b3 -> out f32 (H1; h1 reads finished before b2)
            #pragma unroll
            for (int ci = 0; ci < 2; ++ci) {
                int col = w * 32 + ci * 16 + lr;
                #pragma unroll
                for (int ri = 0; ri < 2; ++ri)
                    #pragma unroll
                    for (int i = 0; i < 4; ++i) {
                        int row = ri * 16 + lk * 4 + i;
                        float v = acc3[ri][ci][i] + bias3[ci];
                        *(float*)(H1 + SWZ(row, row * 512 + col * 4)) = v;
                    }
            }
        } else {
            stream_pair(msg, xn, rn0, sw, 3, lane, n_rows);
        }
        __syncthreads();                                   // b3

        // ================= I3: norm + NT store  ||  feat/glob prefetch =====
        if (is_mlp) {
            #pragma unroll
            for (int pass = 0; pass < 4; ++pass) {
                const int r  = (tid >> 5) + pass * 8;
                const int fl = tid & 31;
                f32x4 v = *(const f32x4*)(H1 + SWZ(r, r * 512 + fl * 16));
                float ss = v[0]*v[0] + v[1]*v[1] + v[2]*v[2] + v[3]*v[3];
                ss += __shfl_xor(ss, 1, 32);
                ss += __shfl_xor(ss, 2, 32);
                ss += __shfl_xor(ss, 4, 32);
                ss += __shfl_xor(ss, 8, 32);
                ss += __shfl_xor(ss, 16, 32);
                float inv = 1.f / (sqrtf(ss) + 1e-8f);
                long long row = r0 + r;
                if (row < n_rows) {
                    f32x4 o = v * inv;
                    __builtin_nontemporal_store(o, (f32x4*)out + row * 32 + fl);
                }
            }
        } else {
            stream_fg(feat, glob, xn, rn0, sw, lane, n_rows);
        }
        __syncthreads();                                   // loop-end barrier
    }
}

// ---------------------------------------------------------------------------
extern "C" void kernel_launch(void* const* d_in, const int* in_sizes, int n_in,
                              void* d_out, int out_size, void* d_ws, size_t ws_size,
                              hipStream_t stream) {
    const float* msg  = (const float*)d_in[0];
    const float* feat = (const float*)d_in[1];
    const float* glob = (const float*)d_in[2];
    const float* W1   = (const float*)d_in[3];
    const float* b1   = (const float*)d_in[4];
    const float* W2   = (const float*)d_in[5];
    const float* b2   = (const float*)d_in[6];
    const float* W3   = (const float*)d_in[7];
    const float* b3   = (const float*)d_in[8];
    float* out = (float*)d_out;

    const int n_rows = in_sizes[1] / 128;   // features is [N,128]
    const int ntiles = (n_rows + 31) / 32;
    const int nblk   = ntiles < 512 ? ntiles : 512;   // 2 blocks/CU resident

    short* pw1 = (short*)d_ws;              // 98304 bf16
    short* pw2 = pw1 + 98304;               // 65536 bf16
    short* pw3 = pw2 + 65536;               // 32768 bf16

    hipLaunchKernelGGL(prep_weights, dim3(768), dim3(256), 0, stream,
                       W1, W2, W3, pw1, pw2, pw3);

    hipLaunchKernelGGL(node_net_pc, dim3(nblk), dim3(512), 0, stream,
                       msg, feat, glob, b1, b2, b3, pw1, pw2, pw3, out,
                       n_rows, ntiles, nblk);
}

// Round 15
// 1091.975 us; speedup vs baseline: 1.7210x; 1.7210x over previous
//
#include <hip/hip_runtime.h>

// ---------------------------------------------------------------------------
// NodeNetwork: agg(sum over deg=16) -> concat(3x128) -> MLP(384-256-256-128)
//              -> row L2 normalize.  N=500000 rows.
// R15: R9 (best, 1080us) with the barrier structure flattened: stage ALL
// inputs (agg via Phase A, feat/glob from entry regs) into one 24KB X region
// before a single sync, then GEMM1 as one uninterrupted 12-ks loop.
// 6 barriers -> 4 (fewer full-wave vmcnt drains; 3x longer B-load hoisting
// window for the scheduler). LDS 40KB (X 24K + H 16K; h2 reuses X[0:16K],
// out reuses H) -> still 4 blocks/CU. No register ring (R4's mistake), no
// other changes vs R9.
// ---------------------------------------------------------------------------

typedef short short8   __attribute__((ext_vector_type(8)));
typedef short short4_t __attribute__((ext_vector_type(4)));
typedef float f32x4    __attribute__((ext_vector_type(4)));

#define SWZ(row, off) ((off) ^ (((row) & 7) << 4))

__device__ __forceinline__ unsigned short f2bf(float f) {
    unsigned int u = __float_as_uint(f);
    u += 0x7fffu + ((u >> 16) & 1u);   // round-to-nearest-even
    return (unsigned short)(u >> 16);
}

// ---------------------------------------------------------------------------
// Weight prep (unchanged): fp32->bf16, per-lane MFMA B-fragment order:
//   pw[((tn*KS + ks)*64 + lane)*8 + j] = bf16( W[k][n] )
//   n = tn*16 + (lane&15), k = ks*32 + (lane>>4)*8 + j
// ---------------------------------------------------------------------------
__global__ void prep_weights(const float* __restrict__ W1,
                             const float* __restrict__ W2,
                             const float* __restrict__ W3,
                             short* __restrict__ pw1,
                             short* __restrict__ pw2,
                             short* __restrict__ pw3) {
    int idx = blockIdx.x * 256 + threadIdx.x;
    if (idx < 98304) {                       // W1 [384][256]
        int j = idx & 7, l = (idx >> 3) & 63, g = idx >> 9;
        int ks = g % 12, tn = g / 12;
        int n = tn * 16 + (l & 15);
        int k = ks * 32 + ((l >> 4) << 3) + j;
        pw1[idx] = (short)f2bf(W1[k * 256 + n]);
    } else if (idx < 98304 + 65536) {        // W2 [256][256]
        int e = idx - 98304;
        int j = e & 7, l = (e >> 3) & 63, g = e >> 9;
        int ks = g & 7, tn = g >> 3;
        int n = tn * 16 + (l & 15);
        int k = ks * 32 + ((l >> 4) << 3) + j;
        pw2[e] = (short)f2bf(W2[k * 256 + n]);
    } else if (idx < 98304 + 65536 + 32768) { // W3 [256][128]
        int e = idx - 98304 - 65536;
        int j = e & 7, l = (e >> 3) & 63, g = e >> 9;
        int ks = g & 7, tn = g >> 3;
        int n = tn * 16 + (l & 15);
        int k = ks * 32 + ((l >> 4) << 3) + j;
        pw3[e] = (short)f2bf(W3[k * 128 + n]);
    }
}

// ---------------------------------------------------------------------------
// Fused kernel: 32 rows/block, 256 threads (4 waves), 40KB LDS, 4 blocks/CU.
//   lds+0     : X  = agg [0:8K] | feat [8K:16K] | glob [16K:24K]
//               (h2 [32][256] bf16 later reuses [0:16K])
//   lds+24576 : H  = h1 [32][256] bf16 (16K); later out [32][128] f32
// ---------------------------------------------------------------------------
__global__ __launch_bounds__(256, 4) void node_net_fused(
    const float* __restrict__ msg,
    const float* __restrict__ feat,
    const float* __restrict__ glob,
    const float* __restrict__ b1v,
    const float* __restrict__ b2v,
    const float* __restrict__ b3v,
    const short* __restrict__ pw1,
    const short* __restrict__ pw2,
    const short* __restrict__ pw3,
    float* __restrict__ out,
    int n_rows)
{
    __shared__ char lds[40960];
    char* XB = lds;
    char* HB = lds + 24576;

    const int tid  = threadIdx.x;
    const int lane = tid & 63;
    const int w    = tid >> 6;
    const int lr   = lane & 15;
    const int lk   = lane >> 4;
    const long long r0 = (long long)blockIdx.x * 32;

    const f32x4 zero4 = {0.f, 0.f, 0.f, 0.f};

    // ---- issue feat/glob NT loads first (as R9) ----
    f32x4 fr[4], gr[4];
    #pragma unroll
    for (int q = 0; q < 4; ++q) {
        int r = (tid >> 5) + q * 8;
        long long row = r0 + r;
        fr[q] = zero4; gr[q] = zero4;
        if (row < n_rows) {
            fr[q] = __builtin_nontemporal_load((const f32x4*)feat + row * 32 + (tid & 31));
            gr[q] = __builtin_nontemporal_load((const f32x4*)glob + row * 32 + (tid & 31));
        }
    }

    // ---- Phase A: msg aggregation -> XB[0:8K] (R9's exact pattern) ----
    #pragma unroll 1
    for (int pp = 0; pp < 4; ++pp) {
        const int rA = 8 * w + 2 * pp;
        const long long rowA = r0 + rA;
        const f32x4* base = (const f32x4*)msg + rowA * 512;
        f32x4 tA[8], tB[8];
        const bool okA = rowA < n_rows;
        const bool okB = (rowA + 1) < n_rows;
        #pragma unroll
        for (int i = 0; i < 8; ++i)
            tA[i] = okA ? __builtin_nontemporal_load(base + i * 64 + lane) : zero4;
        #pragma unroll
        for (int i = 0; i < 8; ++i)
            tB[i] = okB ? __builtin_nontemporal_load(base + 512 + i * 64 + lane) : zero4;
        f32x4 sA = ((tA[0]+tA[1])+(tA[2]+tA[3])) + ((tA[4]+tA[5])+(tA[6]+tA[7]));
        f32x4 sB = ((tB[0]+tB[1])+(tB[2]+tB[3])) + ((tB[4]+tB[5])+(tB[6]+tB[7]));
        #pragma unroll
        for (int c = 0; c < 4; ++c) {
            sA[c] += __shfl_xor(sA[c], 32);
            sB[c] += __shfl_xor(sB[c], 32);
        }
        f32x4 s = (lane < 32) ? sA : sB;
        short4_t s4;
        s4[0] = (short)f2bf(s[0]); s4[1] = (short)f2bf(s[1]);
        s4[2] = (short)f2bf(s[2]); s4[3] = (short)f2bf(s[3]);
        const int orow = rA + (lane >> 5);
        *(short4_t*)(XB + SWZ(orow, orow * 256 + (lane & 31) * 8)) = s4;
    }

    // ---- stage feat/glob regs -> XB[8K:24K] (before the single sync) ----
    #pragma unroll
    for (int q = 0; q < 4; ++q) {
        int r = (tid >> 5) + q * 8;
        short4_t sf, sg;
        sf[0] = (short)f2bf(fr[q][0]); sf[1] = (short)f2bf(fr[q][1]);
        sf[2] = (short)f2bf(fr[q][2]); sf[3] = (short)f2bf(fr[q][3]);
        sg[0] = (short)f2bf(gr[q][0]); sg[1] = (short)f2bf(gr[q][1]);
        sg[2] = (short)f2bf(gr[q][2]); sg[3] = (short)f2bf(gr[q][3]);
        *(short4_t*)(XB + 8192  + SWZ(r, r * 256 + (tid & 31) * 8)) = sf;
        *(short4_t*)(XB + 16384 + SWZ(r, r * 256 + (tid & 31) * 8)) = sg;
    }
    __syncthreads();                                   // sync1

    // ================= GEMM1: one uninterrupted 12-ks loop =================
    f32x4 acc1[2][4];
    #pragma unroll
    for (int ri = 0; ri < 2; ++ri)
        #pragma unroll
        for (int ci = 0; ci < 4; ++ci) acc1[ri][ci] = zero4;

    #pragma unroll
    for (int ks = 0; ks < 12; ++ks) {
        const int p = ks >> 2, s = ks & 3;
        short8 a[2], b[4];
        #pragma unroll
        for (int ri = 0; ri < 2; ++ri) {
            int row = ri * 16 + lr;
            a[ri] = *(const short8*)(XB + p * 8192 + SWZ(row, row * 256 + s * 64 + lk * 16));
        }
        #pragma unroll
        for (int ci = 0; ci < 4; ++ci)
            b[ci] = *(const short8*)(pw1 + ((((w * 4 + ci) * 12 + ks) * 64 + lane) << 3));
        #pragma unroll
        for (int ri = 0; ri < 2; ++ri)
            #pragma unroll
            for (int ci = 0; ci < 4; ++ci)
                acc1[ri][ci] = __builtin_amdgcn_mfma_f32_16x16x32_bf16(
                    a[ri], b[ci], acc1[ri][ci], 0, 0, 0);
    }

    // ---- epilogue 1: +b1, ReLU, bf16 -> h1 in HB ----
    #pragma unroll
    for (int ci = 0; ci < 4; ++ci) {
        int col = w * 64 + ci * 16 + lr;
        float bias = b1v[col];
        #pragma unroll
        for (int ri = 0; ri < 2; ++ri)
            #pragma unroll
            for (int i = 0; i < 4; ++i) {
                int row = ri * 16 + lk * 4 + i;
                float v = fmaxf(acc1[ri][ci][i] + bias, 0.f);
                *(short*)(HB + SWZ(row, row * 512 + col * 2)) = (short)f2bf(v);
            }
    }
    __syncthreads();                                   // sync2

    // ================= GEMM2: h1 @ W2 (reads HB) ===========================
    f32x4 acc2[2][4];
    #pragma unroll
    for (int ri = 0; ri < 2; ++ri)
        #pragma unroll
        for (int ci = 0; ci < 4; ++ci) acc2[ri][ci] = zero4;

    #pragma unroll
    for (int s = 0; s < 8; ++s) {
        short8 a[2], b[4];
        #pragma unroll
        for (int ri = 0; ri < 2; ++ri) {
            int row = ri * 16 + lr;
            a[ri] = *(const short8*)(HB + SWZ(row, row * 512 + s * 64 + lk * 16));
        }
        #pragma unroll
        for (int ci = 0; ci < 4; ++ci)
            b[ci] = *(const short8*)(pw2 + ((((w * 4 + ci) * 8 + s) * 64 + lane) << 3));
        #pragma unroll
        for (int ri = 0; ri < 2; ++ri)
            #pragma unroll
            for (int ci = 0; ci < 4; ++ci)
                acc2[ri][ci] = __builtin_amdgcn_mfma_f32_16x16x32_bf16(
                    a[ri], b[ci], acc2[ri][ci], 0, 0, 0);
    }

    // ---- epilogue 2: +b2, ReLU, bf16 -> h2 in XB[0:16K] (X dead) ----
    #pragma unroll
    for (int ci = 0; ci < 4; ++ci) {
        int col = w * 64 + ci * 16 + lr;
        float bias = b2v[col];
        #pragma unroll
        for (int ri = 0; ri < 2; ++ri)
            #pragma unroll
            for (int i = 0; i < 4; ++i) {
                int row = ri * 16 + lk * 4 + i;
                float v = fmaxf(acc2[ri][ci][i] + bias, 0.f);
                *(short*)(XB + SWZ(row, row * 512 + col * 2)) = (short)f2bf(v);
            }
    }
    __syncthreads();                                   // sync3

    // ================= GEMM3: h2 @ W3 (reads XB) ===========================
    f32x4 acc3[2][2];
    #pragma unroll
    for (int ri = 0; ri < 2; ++ri)
        #pragma unroll
        for (int ci = 0; ci < 2; ++ci) acc3[ri][ci] = zero4;

    #pragma unroll
    for (int s = 0; s < 8; ++s) {
        short8 a[2], b[2];
        #pragma unroll
        for (int ri = 0; ri < 2; ++ri) {
            int row = ri * 16 + lr;
            a[ri] = *(const short8*)(XB + SWZ(row, row * 512 + s * 64 + lk * 16));
        }
        #pragma unroll
        for (int ci = 0; ci < 2; ++ci)
            b[ci] = *(const short8*)(pw3 + ((((w * 2 + ci) * 8 + s) * 64 + lane) << 3));
        #pragma unroll
        for (int ri = 0; ri < 2; ++ri)
            #pragma unroll
            for (int ci = 0; ci < 2; ++ci)
                acc3[ri][ci] = __builtin_amdgcn_mfma_f32_16x16x32_bf16(
                    a[ri], b[ci], acc3[ri][ci], 0, 0, 0);
    }

    // ---- epilogue 3: +b3, f32 -> out tile in HB (h1 dead) ----
    #pragma unroll
    for (int ci = 0; ci < 2; ++ci) {
        int col = w * 32 + ci * 16 + lr;
        float bias = b3v[col];
        #pragma unroll
        for (int ri = 0; ri < 2; ++ri)
            #pragma unroll
            for (int i = 0; i < 4; ++i) {
                int row = ri * 16 + lk * 4 + i;
                float v = acc3[ri][ci][i] + bias;
                *(float*)(HB + SWZ(row, row * 512 + col * 4)) = v;
            }
    }
    __syncthreads();                                   // sync4

    // ---- row-wise L2 normalize + coalesced NT store ----
    #pragma unroll
    for (int pass = 0; pass < 4; ++pass) {
        const int r  = (tid >> 5) + pass * 8;
        const int fl = tid & 31;
        f32x4 v = *(const f32x4*)(HB + SWZ(r, r * 512 + fl * 16));
        float ss = v[0]*v[0] + v[1]*v[1] + v[2]*v[2] + v[3]*v[3];
        ss += __shfl_xor(ss, 1, 32);
        ss += __shfl_xor(ss, 2, 32);
        ss += __shfl_xor(ss, 4, 32);
        ss += __shfl_xor(ss, 8, 32);
        ss += __shfl_xor(ss, 16, 32);
        float inv = 1.f / (sqrtf(ss) + 1e-8f);
        long long row = r0 + r;
        if (row < n_rows) {
            f32x4 o = v * inv;
            __builtin_nontemporal_store(o, (f32x4*)out + row * 32 + fl);
        }
    }
}

// ---------------------------------------------------------------------------
extern "C" void kernel_launch(void* const* d_in, const int* in_sizes, int n_in,
                              void* d_out, int out_size, void* d_ws, size_t ws_size,
                              hipStream_t stream) {
    const float* msg  = (const float*)d_in[0];
    const float* feat = (const float*)d_in[1];
    const float* glob = (const float*)d_in[2];
    const float* W1   = (const float*)d_in[3];
    const float* b1   = (const float*)d_in[4];
    const float* W2   = (const float*)d_in[5];
    const float* b2   = (const float*)d_in[6];
    const float* W3   = (const float*)d_in[7];
    const float* b3   = (const float*)d_in[8];
    float* out = (float*)d_out;

    const int n_rows = in_sizes[1] / 128;   // features is [N,128]

    short* pw1 = (short*)d_ws;              // 98304 bf16
    short* pw2 = pw1 + 98304;               // 65536 bf16
    short* pw3 = pw2 + 65536;               // 32768 bf16

    hipLaunchKernelGGL(prep_weights, dim3(768), dim3(256), 0, stream,
                       W1, W2, W3, pw1, pw2, pw3);

    const int nblocks = (n_rows + 31) / 32;
    hipLaunchKernelGGL(node_net_fused, dim3(nblocks), dim3(256), 0, stream,
                       msg, feat, glob, b1, b2, b3, pw1, pw2, pw3, out, n_rows);
}